// Round 3
// baseline (387.764 us; speedup 1.0000x reference)
//
#include <hip/hip_runtime.h>
#include <stdint.h>

typedef __bf16 bf16;
typedef __bf16 bf16x4 __attribute__((ext_vector_type(4)));
typedef __bf16 bf16x8 __attribute__((ext_vector_type(8)));
typedef float f32x4 __attribute__((ext_vector_type(4)));
typedef float f32x16 __attribute__((ext_vector_type(16)));

#define DM 2048   // embed dim = N = K of GEMMs
#define MM 4096   // B*S rows
#define MFMA16(a, b, c) __builtin_amdgcn_mfma_f32_16x16x32_bf16(a, b, c, 0, 0, 0)
#define MFMA32(a, b, c) __builtin_amdgcn_mfma_f32_32x32x16_bf16(a, b, c, 0, 0, 0)

__device__ __forceinline__ void gload_lds16(const void* g, void* l) {
  __builtin_amdgcn_global_load_lds((const __attribute__((address_space(1))) uint32_t*)g,
                                   (__attribute__((address_space(3))) uint32_t*)l, 16, 0, 0);
}

// fp32 -> bf16 for x (8.4M) and the 4 weight matrices (4.2M each).
__global__ __launch_bounds__(256) void cvt_f32_bf16(
    const float* __restrict__ s0, const float* __restrict__ s1,
    const float* __restrict__ s2, const float* __restrict__ s3,
    const float* __restrict__ s4,
    bf16* __restrict__ d0, bf16* __restrict__ d1, bf16* __restrict__ d2,
    bf16* __restrict__ d3, bf16* __restrict__ d4)
{
  const size_t i4 = (size_t)(blockIdx.x * 256 + threadIdx.x) * 4;  // float index
  const float* s; bf16* d; size_t off;
  if      (i4 <  8388608u) { s = s0; d = d0; off = i4;             }
  else if (i4 < 12582912u) { s = s1; d = d1; off = i4 -  8388608u; }
  else if (i4 < 16777216u) { s = s2; d = d2; off = i4 - 12582912u; }
  else if (i4 < 20971520u) { s = s3; d = d3; off = i4 - 16777216u; }
  else                     { s = s4; d = d4; off = i4 - 20971520u; }
  const float4 v = *(const float4*)(s + off);
  bf16x4 o = { (bf16)v.x, (bf16)v.y, (bf16)v.z, (bf16)v.w };
  *(bf16x4*)(d + off) = o;
}

// Fused QKV projection, v2: BK=32 double-buffered single-barrier pipeline
// (stage t+1 before computing t; one __syncthreads/K-step -> the vmcnt drain
// lands after a full compute phase). LDS rows pack TWO m-rows (row = m>>1,
// slot = ((m&1)*4 + k8) ^ (row&7)) so rows stay 128B and the granule-XOR
// swizzle keeps ds_read_b128 conflict-free at BK=32. A staged once for
// 48 MFMAs/K-step/wave across 3 W matrices. RoPE + scale fused in epilogue.
// XCD swizzle: each XCD owns 2 n-columns (3 MB weights L2-resident).
__global__ __launch_bounds__(256, 2) void gemm_qkv_fused(
    const bf16* __restrict__ A,
    const bf16* __restrict__ Wq, const bf16* __restrict__ Wk, const bf16* __restrict__ Wv,
    const float* __restrict__ qb, const float* __restrict__ kb, const float* __restrict__ vb,
    bf16* __restrict__ Cq, bf16* __restrict__ Ck, bf16* __restrict__ Cv)
{
  __shared__ __align__(16) bf16 smem[32768];   // 64 KB
  // layout: A dbuf 2x4096 at [0]; W[z] dbuf 2x4096 at [8192 + (z*2+nb)*4096]

  const int id = blockIdx.x;               // 512 blocks
  const int xcd = id & 7, jj = id >> 3;
  const int n0 = (xcd * 2 + (jj >> 5)) * 128;
  const int m0 = (jj & 31) * 128;

  const int t = threadIdx.x;
  const int wave = t >> 6, lane = t & 63;
  const int quad = lane >> 4, c16 = lane & 15;
  const int wr = wave >> 1, wc = wave & 1;

  f32x4 acc[3][4][4] = {};

  // --- staging descriptors: granule g = rr*256 + t -> LDS row=g>>3, slot=g&7;
  // inverse swizzle on the GLOBAL source: s' = slot ^ (row&7),
  // m = 2*row + (s'>>2), k8 = s'&3  (G21 both-sides-or-neither).
  size_t aRow[2], wRow[2]; int ldsOff[2];
#pragma unroll
  for (int rr = 0; rr < 2; ++rr) {
    const int g = rr * 256 + t;
    const int r = g >> 3, s = g & 7;
    const int sp = s ^ (r & 7);
    const int m = 2 * r + (sp >> 2), k8 = sp & 3;
    aRow[rr] = (size_t)(m0 + m) * DM + k8 * 8;
    wRow[rr] = (size_t)(n0 + m) * DM + k8 * 8;
    ldsOff[rr] = (rr * 256 + wave * 64) * 8;
  }
  // --- read indices (element offsets within one 4096-elem buffer)
  int aIdx[4], bIdx[4];
#pragma unroll
  for (int i = 0; i < 4; ++i) {
    const int ma = wr * 64 + i * 16 + c16;
    aIdx[i] = (ma >> 1) * 64 + (((((ma & 1) << 2) | quad)) ^ ((ma >> 1) & 7)) * 8;
    const int mb = wc * 64 + i * 16 + c16;
    bIdx[i] = (mb >> 1) * 64 + (((((mb & 1) << 2) | quad)) ^ ((mb >> 1) & 7)) * 8;
  }

  auto stage = [&](int k0, int nb) {
#pragma unroll
    for (int rr = 0; rr < 2; ++rr) {
      gload_lds16(A  + aRow[rr] + k0, smem + nb * 4096 + ldsOff[rr]);
      gload_lds16(Wq + wRow[rr] + k0, smem + 8192 + (0 + nb) * 4096 + ldsOff[rr]);
      gload_lds16(Wk + wRow[rr] + k0, smem + 8192 + (2 + nb) * 4096 + ldsOff[rr]);
      gload_lds16(Wv + wRow[rr] + k0, smem + 8192 + (4 + nb) * 4096 + ldsOff[rr]);
    }
  };

  stage(0, 0);
  __syncthreads();

#pragma unroll 2
  for (int kt = 0; kt < 64; ++kt) {
    const int cb = kt & 1;
    if (kt < 63) stage((kt + 1) * 32, cb ^ 1);   // overlaps with compute below

    bf16x8 af[4];
#pragma unroll
    for (int i = 0; i < 4; ++i) af[i] = *(const bf16x8*)&smem[cb * 4096 + aIdx[i]];
#pragma unroll
    for (int z = 0; z < 3; ++z) {
      const bf16* Wb = smem + 8192 + (z * 2 + cb) * 4096;
      bf16x8 bfr[4];
#pragma unroll
      for (int jx = 0; jx < 4; ++jx) bfr[jx] = *(const bf16x8*)&Wb[bIdx[jx]];
#pragma unroll
      for (int i = 0; i < 4; ++i)
#pragma unroll
        for (int jx = 0; jx < 4; ++jx)
          acc[z][i][jx] = MFMA16(af[i], bfr[jx], acc[z][i][jx]);
    }
    __syncthreads();   // drains stage(kt+1) vmcnt; protects both buffers
  }

  // ---- V epilogue: transposed to (B*H, Dh, S), bf16x4 along s ----
  const int h = n0 >> 7;   // one head per 128-wide n-column
#pragma unroll
  for (int jx = 0; jx < 4; ++jx) {
    const int d = wc * 64 + jx * 16 + c16;
    const float bv = vb[n0 + d];
#pragma unroll
    for (int i = 0; i < 4; ++i) {
      const int row = m0 + wr * 64 + i * 16 + quad * 4;
      const int b = row >> 11, s = row & 2047;
      bf16x4 o;
#pragma unroll
      for (int r = 0; r < 4; ++r) o[r] = (bf16)(acc[2][i][jx][r] + bv);
      *(bf16x4*)&Cv[((size_t)((b * 16 + h) * 128 + d)) * 2048 + s] = o;
    }
  }

  // ---- Q/K epilogues: bias + RoPE via LDS round-trip (pair d <-> d+64
  // crosses waves). Q additionally scaled by log2e/sqrt(Dh) for exp2 softmax.
  bf16* Tl = smem;  // [128][136], 34.8 KB, 16B-aligned rows
#pragma unroll
  for (int z = 0; z < 2; ++z) {
    __syncthreads();   // smem free (main loop done / previous z consumed)
#pragma unroll
    for (int jx = 0; jx < 4; ++jx) {
      const int col = wc * 64 + jx * 16 + c16;
      const float bv = (z == 0 ? qb : kb)[n0 + col];
#pragma unroll
      for (int i = 0; i < 4; ++i) {
        const int row = wr * 64 + i * 16 + quad * 4;
#pragma unroll
        for (int r = 0; r < 4; ++r)
          Tl[(row + r) * 136 + col] = (bf16)(acc[z][i][jx][r] + bv);
      }
    }
    __syncthreads();
    bf16* C = (z == 0) ? Cq : Ck;
    const float scale = (z == 0) ? 0.08838834764831845f * 1.4426950408889634f : 1.0f;
#pragma unroll
    for (int rr = 0; rr < 4; ++rr) {
      const int row = rr * 32 + (t >> 3);
      const int d0 = (t & 7) * 8;
      const int s = (m0 + row) & 2047;
      bf16x8 xa = *(const bf16x8*)&Tl[row * 136 + d0];
      bf16x8 xb = *(const bf16x8*)&Tl[row * 136 + d0 + 64];
      bf16x8 o1, o2;
#pragma unroll
      for (int j = 0; j < 8; ++j) {
        const float inv_freq = __expf((float)(d0 + j) * -0.14391156514261228f);
        float sn, cs;
        __sincosf((float)s * inv_freq, &sn, &cs);
        const float a = (float)xa[j], bb = (float)xb[j];
        o1[j] = (bf16)((a * cs - bb * sn) * scale);
        o2[j] = (bf16)((bb * cs + a * sn) * scale);
      }
      *(bf16x8*)&C[(size_t)(m0 + row) * DM + n0 + d0]      = o1;
      *(bf16x8*)&C[(size_t)(m0 + row) * DM + n0 + d0 + 64] = o2;
    }
  }
}

// Output projection GEMM + bias (fp32 out), v2: same BK=32 dbuf single-barrier
// pipeline + packed-row swizzle. 32 KB LDS -> 3 blocks/CU.
__global__ __launch_bounds__(256, 3) void gemm_bias_f32(
    const bf16* __restrict__ A, const bf16* __restrict__ W,
    const float* __restrict__ bias, float* __restrict__ C)
{
  __shared__ __align__(16) bf16 smem[16384];   // 32 KB: A dbuf 2x4096, B dbuf 2x4096
  const int id = blockIdx.x;               // 512 blocks
  const int xcd = id & 7, jj = id >> 3;
  const int n0 = (xcd * 2 + (jj >> 5)) * 128;
  const int m0 = (jj & 31) * 128;

  const int t = threadIdx.x;
  const int wave = t >> 6, lane = t & 63;
  const int quad = lane >> 4, c16 = lane & 15;
  const int wr = wave >> 1, wc = wave & 1;

  f32x4 acc[4][4] = {};

  size_t aRow[2], bRow[2]; int ldsOff[2];
#pragma unroll
  for (int rr = 0; rr < 2; ++rr) {
    const int g = rr * 256 + t;
    const int r = g >> 3, s = g & 7;
    const int sp = s ^ (r & 7);
    const int m = 2 * r + (sp >> 2), k8 = sp & 3;
    aRow[rr] = (size_t)(m0 + m) * DM + k8 * 8;
    bRow[rr] = (size_t)(n0 + m) * DM + k8 * 8;
    ldsOff[rr] = (rr * 256 + wave * 64) * 8;
  }
  int aIdx[4], bIdx[4];
#pragma unroll
  for (int i = 0; i < 4; ++i) {
    const int ma = wr * 64 + i * 16 + c16;
    aIdx[i] = (ma >> 1) * 64 + (((((ma & 1) << 2) | quad)) ^ ((ma >> 1) & 7)) * 8;
    const int mb = wc * 64 + i * 16 + c16;
    bIdx[i] = (mb >> 1) * 64 + (((((mb & 1) << 2) | quad)) ^ ((mb >> 1) & 7)) * 8;
  }

  auto stage = [&](int k0, int nb) {
#pragma unroll
    for (int rr = 0; rr < 2; ++rr) {
      gload_lds16(A + aRow[rr] + k0, smem + nb * 4096 + ldsOff[rr]);
      gload_lds16(W + bRow[rr] + k0, smem + 8192 + nb * 4096 + ldsOff[rr]);
    }
  };

  stage(0, 0);
  __syncthreads();

#pragma unroll 2
  for (int kt = 0; kt < 64; ++kt) {
    const int cb = kt & 1;
    if (kt < 63) stage((kt + 1) * 32, cb ^ 1);

    bf16x8 af[4], bfr[4];
#pragma unroll
    for (int i = 0; i < 4; ++i) {
      af[i]  = *(const bf16x8*)&smem[cb * 4096 + aIdx[i]];
      bfr[i] = *(const bf16x8*)&smem[8192 + cb * 4096 + bIdx[i]];
    }
#pragma unroll
    for (int i = 0; i < 4; ++i)
#pragma unroll
      for (int jx = 0; jx < 4; ++jx)
        acc[i][jx] = MFMA16(af[i], bfr[jx], acc[i][jx]);
    __syncthreads();
  }

#pragma unroll
  for (int jx = 0; jx < 4; ++jx) {
    const int col = n0 + wc * 64 + jx * 16 + c16;
    const float bv = bias[col];
#pragma unroll
    for (int i = 0; i < 4; ++i) {
      const int row = m0 + wr * 64 + i * 16 + quad * 4;
#pragma unroll
      for (int r = 0; r < 4; ++r)
        C[(size_t)(row + r) * DM + col] = acc[i][jx][r] + bv;
    }
  }
}

// Flash attention v3: 32x32x16 MFMA, register-resident P (cvt_pk +
// permlane32_swap redistribution, T12), 64-key double-buffered tiles,
// granule-XOR-swizzled K/V LDS (g ^= row&7, pre-swizzled global source).
// Per wave: 32 q-rows; QK^T output S^T[key][q]: key=(reg&3)+8*(reg>>2)+4h,
// q=lane&31. PV B-operand needs key=8h+j -> one permlane32_swap per
// cvt_pk pair fixes the half mismatch. No Ps LDS at all. LDS 64 KB.
__global__ __launch_bounds__(256, 2) void attn(
    const bf16* __restrict__ Q, const bf16* __restrict__ K,
    const bf16* __restrict__ Vt, bf16* __restrict__ O)
{
  __shared__ __align__(16) bf16 Ks[2][64][128];   // [buf][key][dh]   32 KB
  __shared__ __align__(16) bf16 Vs[2][128][64];   // [buf][d][key]    32 KB
  const int t = threadIdx.x;
  const int wave = t >> 6, lane = t & 63;
  const int r31 = lane & 31, h = lane >> 5;
  const int id = blockIdx.x;               // 512 blocks
  const int xcd = id & 7, jj = id >> 3;
  const int bh = xcd * 4 + (jj >> 4);
  const int q0 = (jj & 15) * 128;
  const int b = bh >> 4, hd = bh & 15;

  // Q fragments (B-operand): lane holds Q[q = r31][dh = ks*16 + h*8 + j]
  bf16x8 qf[8];
  {
    const bf16* qrow = Q + (size_t)(b * 2048 + q0 + wave * 32 + r31) * 2048
                         + (size_t)hd * 128 + h * 8;
#pragma unroll
    for (int ks = 0; ks < 8; ++ks) qf[ks] = *(const bf16x8*)(qrow + ks * 16);
  }

  float l_i = 0.f;
  f32x16 o_acc[4] = {};   // O^T[d = db*32 + (reg&3)+8*(reg>>2)+4h][q = r31]

  const bf16* Kg = K + (size_t)(b * 2048) * 2048 + (size_t)hd * 128;
  const bf16* Vg = Vt + (size_t)bh * 128 * 2048;

  // stage one 64-key tile (16 KB K + 16 KB V). LDS dest linear; swizzle on
  // the per-lane GLOBAL source column (G21 both-sides-or-neither).
  auto stage = [&](int kt0, int nb) {
#pragma unroll
    for (int rr = 0; rr < 4; ++rr) {
      const int G = rr * 256 + t;
      const int key = G >> 4, gl = G & 15;   // row, 16B-granule in row
      gload_lds16(Kg + (size_t)(kt0 + key) * 2048 + ((gl ^ (key & 7)) * 8),
                  (bf16*)Ks[nb] + (rr * 256 + wave * 64) * 8);
    }
#pragma unroll
    for (int rr = 0; rr < 4; ++rr) {
      const int G = rr * 256 + t;
      const int d = G >> 3, gl = G & 7;
      gload_lds16(Vg + (size_t)d * 2048 + kt0 + ((gl ^ (d & 7)) * 8),
                  (bf16*)Vs[nb] + (rr * 256 + wave * 64) * 8);
    }
  };

  stage(0, 0);
  __syncthreads();

#pragma unroll 2
  for (int kt = 0; kt < 32; ++kt) {
    const int cb = kt & 1;
    if (kt < 31) stage((kt + 1) * 64, cb ^ 1);   // overlaps with compute below

#pragma unroll
    for (int rb = 0; rb < 2; ++rb) {
      // S^T[32 keys][32 q] for key-row-block rb
      f32x16 st = {};
#pragma unroll
      for (int ks = 0; ks < 8; ++ks) {
        const int key = rb * 32 + r31;
        const int g = (2 * ks + h) ^ (key & 7);
        bf16x8 kf = *(const bf16x8*)&Ks[cb][key][g * 8];
        st = MFMA32(kf, qf[ks], st);
      }

      // exp2 softmax (no max); P stays in registers
      float p[16];
#pragma unroll
      for (int r = 0; r < 16; ++r) { p[r] = exp2f(st[r]); l_i += p[r]; }

      // pack pairs: pka[pp] = keys(4h+8pp, +1), pkb[pp] = keys(4h+8pp+2, +3)
      uint32_t pka[4], pkb[4];
#pragma unroll
      for (int pp = 0; pp < 4; ++pp) {
        asm("v_cvt_pk_bf16_f32 %0, %1, %2"
            : "=v"(pka[pp]) : "v"(p[4 * pp + 0]), "v"(p[4 * pp + 1]));
        asm("v_cvt_pk_bf16_f32 %0, %1, %2"
            : "=v"(pkb[pp]) : "v"(p[4 * pp + 2]), "v"(p[4 * pp + 3]));
      }

      // per 16-key chunk c: swap halves -> B-frag words in ascending key order
#pragma unroll
      for (int c = 0; c < 2; ++c) {
        uint32_t a0 = pka[2 * c], a1 = pka[2 * c + 1];
        uint32_t b0 = pkb[2 * c], b1 = pkb[2 * c + 1];
        asm("v_permlane32_swap_b32 %0, %1" : "+v"(a0), "+v"(a1));
        asm("v_permlane32_swap_b32 %0, %1" : "+v"(b0), "+v"(b1));
        union { uint32_t u[4]; bf16x8 v; } pf;
        pf.u[0] = a0; pf.u[1] = b0; pf.u[2] = a1; pf.u[3] = b1;
        const int kap = rb * 2 + c;   // 16-key chunk within the 64-key tile
#pragma unroll
        for (int db = 0; db < 4; ++db) {
          const int d = db * 32 + r31;
          const int g = (2 * kap + h) ^ (d & 7);
          bf16x8 vf = *(const bf16x8*)&Vs[cb][d][g * 8];
          o_acc[db] = MFMA32(vf, pf.v, o_acc[db]);
        }
      }
    }
    __syncthreads();  // drains stage(kt+1) vmcnt; protects both buffers
  }

  // epilogue: l reduce across the two key-halves (h pair), normalize, write O
  l_i += __shfl_xor(l_i, 32, 64);
  const float invl = 1.0f / l_i;
  const int q = q0 + wave * 32 + r31;
  bf16* orow = O + (size_t)(b * 2048 + q) * 2048 + (size_t)hd * 128;
#pragma unroll
  for (int db = 0; db < 4; ++db)
#pragma unroll
    for (int pp = 0; pp < 4; ++pp) {
      const int d0 = db * 32 + 8 * pp + 4 * h;
      bf16x4 o;
#pragma unroll
      for (int r = 0; r < 4; ++r) o[r] = (bf16)(o_acc[db][4 * pp + r] * invl);
      *(bf16x4*)(orow + d0) = o;
    }
}

extern "C" void kernel_launch(void* const* d_in, const int* in_sizes, int n_in,
                              void* d_out, int out_size, void* d_ws, size_t ws_size,
                              hipStream_t stream)
{
  (void)in_sizes; (void)n_in; (void)out_size; (void)ws_size;
  const float* x   = (const float*)d_in[0];
  const float* q_w = (const float*)d_in[1];
  const float* k_w = (const float*)d_in[2];
  const float* v_w = (const float*)d_in[3];
  const float* q_b = (const float*)d_in[4];
  const float* k_b = (const float*)d_in[5];
  const float* v_b = (const float*)d_in[6];
  const float* o_w = (const float*)d_in[7];
  const float* o_b = (const float*)d_in[8];

  const size_t NELEM = (size_t)MM * DM;   // 8388608
  const size_t WELEM = (size_t)DM * DM;   // 4194304
  bf16* Xb  = (bf16*)d_ws;                // reused as attnO (x dead by then)
  bf16* Wq  = Xb + NELEM;
  bf16* Wk  = Wq + WELEM;
  bf16* Wv  = Wk + WELEM;
  bf16* Wo  = Wv + WELEM;
  bf16* Q   = Wo + WELEM;
  bf16* Kb  = Q  + NELEM;
  bf16* Vt  = Kb + NELEM;
  bf16* attnO = Xb;

  cvt_f32_bf16<<<24576, 256, 0, stream>>>(x, q_w, k_w, v_w, o_w, Xb, Wq, Wk, Wv, Wo);

  gemm_qkv_fused<<<512, 256, 0, stream>>>(Xb, Wq, Wk, Wv, q_b, k_b, v_b, Q, Kb, Vt);
  attn<<<512, 256, 0, stream>>>(Q, Kb, Vt, attnO);
  gemm_bias_f32<<<512, 256, 0, stream>>>(attnO, Wo, o_b, (float*)d_out);
}

// Round 5
// 383.930 us; speedup vs baseline: 1.0100x; 1.0100x over previous
//
#include <hip/hip_runtime.h>
#include <stdint.h>

typedef __bf16 bf16;
typedef __bf16 bf16x4 __attribute__((ext_vector_type(4)));
typedef __bf16 bf16x8 __attribute__((ext_vector_type(8)));
typedef float f32x4 __attribute__((ext_vector_type(4)));
typedef float f32x16 __attribute__((ext_vector_type(16)));

#define DM 2048   // embed dim = N = K of GEMMs
#define MM 4096   // B*S rows
#define MFMA16(a, b, c) __builtin_amdgcn_mfma_f32_16x16x32_bf16(a, b, c, 0, 0, 0)
#define MFMA32(a, b, c) __builtin_amdgcn_mfma_f32_32x32x16_bf16(a, b, c, 0, 0, 0)

// counted-vmcnt barrier pair (T4): wait only the N newest-excluded loads,
// single asm block so the compiler can't hoist ds_reads across (memory clobber).
#define WAITV_BAR(N) asm volatile("s_waitcnt vmcnt(" #N ")\n\ts_barrier" ::: "memory")
#define BAR()        asm volatile("s_barrier" ::: "memory")

__device__ __forceinline__ void gload_lds16(const void* g, void* l) {
  __builtin_amdgcn_global_load_lds((const __attribute__((address_space(1))) uint32_t*)g,
                                   (__attribute__((address_space(3))) uint32_t*)l, 16, 0, 0);
}

// fp32 -> bf16 for x (8.4M) and the 4 weight matrices (4.2M each).
__global__ __launch_bounds__(256) void cvt_f32_bf16(
    const float* __restrict__ s0, const float* __restrict__ s1,
    const float* __restrict__ s2, const float* __restrict__ s3,
    const float* __restrict__ s4,
    bf16* __restrict__ d0, bf16* __restrict__ d1, bf16* __restrict__ d2,
    bf16* __restrict__ d3, bf16* __restrict__ d4)
{
  const size_t i4 = (size_t)(blockIdx.x * 256 + threadIdx.x) * 4;  // float index
  const float* s; bf16* d; size_t off;
  if      (i4 <  8388608u) { s = s0; d = d0; off = i4;             }
  else if (i4 < 12582912u) { s = s1; d = d1; off = i4 -  8388608u; }
  else if (i4 < 16777216u) { s = s2; d = d2; off = i4 - 12582912u; }
  else if (i4 < 20971520u) { s = s3; d = d3; off = i4 - 16777216u; }
  else                     { s = s4; d = d4; off = i4 - 20971520u; }
  const float4 v = *(const float4*)(s + off);
  bf16x4 o = { (bf16)v.x, (bf16)v.y, (bf16)v.z, (bf16)v.w };
  *(bf16x4*)(d + off) = o;
}

// Fused QKV projection, v3: BK=32 double-buffered with COUNTED vmcnt —
// stage(t+1) is issued in iter t but only waited at the top of iter t+1
// (vmcnt(8)), so each tile's loads get a full iteration of latency cover.
// Two raw s_barriers per iter: {vmcnt(8)+bar -> compute -> bar}.
// LDS rows pack TWO m-rows (row = m>>1, slot = ((m&1)*4 + k8) ^ (row&7));
// granule-XOR keeps ds_read_b128 conflict-free. RoPE + scale in epilogue.
// XCD swizzle: each XCD owns 2 n-columns (3 MB weights L2-resident).
__global__ __launch_bounds__(256, 2) void gemm_qkv_fused(
    const bf16* __restrict__ A,
    const bf16* __restrict__ Wq, const bf16* __restrict__ Wk, const bf16* __restrict__ Wv,
    const float* __restrict__ qb, const float* __restrict__ kb, const float* __restrict__ vb,
    bf16* __restrict__ Cq, bf16* __restrict__ Ck, bf16* __restrict__ Cv)
{
  __shared__ __align__(16) bf16 smem[32768];   // 64 KB
  // layout: A dbuf 2x4096 at [0]; W[z] dbuf 2x4096 at [8192 + (z*2+nb)*4096]

  const int id = blockIdx.x;               // 512 blocks
  const int xcd = id & 7, jj = id >> 3;
  const int n0 = (xcd * 2 + (jj >> 5)) * 128;
  const int m0 = (jj & 31) * 128;

  const int t = threadIdx.x;
  const int wave = t >> 6, lane = t & 63;
  const int quad = lane >> 4, c16 = lane & 15;
  const int wr = wave >> 1, wc = wave & 1;

  f32x4 acc[3][4][4] = {};

  // --- staging descriptors: granule g = rr*256 + t -> LDS row=g>>3, slot=g&7;
  // inverse swizzle on the GLOBAL source: s' = slot ^ (row&7),
  // m = 2*row + (s'>>2), k8 = s'&3  (G21 both-sides-or-neither).
  size_t aRow[2], wRow[2]; int ldsOff[2];
#pragma unroll
  for (int rr = 0; rr < 2; ++rr) {
    const int g = rr * 256 + t;
    const int r = g >> 3, s = g & 7;
    const int sp = s ^ (r & 7);
    const int m = 2 * r + (sp >> 2), k8 = sp & 3;
    aRow[rr] = (size_t)(m0 + m) * DM + k8 * 8;
    wRow[rr] = (size_t)(n0 + m) * DM + k8 * 8;
    ldsOff[rr] = (rr * 256 + wave * 64) * 8;
  }
  // --- read indices (element offsets within one 4096-elem buffer)
  int aIdx[4], bIdx[4];
#pragma unroll
  for (int i = 0; i < 4; ++i) {
    const int ma = wr * 64 + i * 16 + c16;
    aIdx[i] = (ma >> 1) * 64 + (((((ma & 1) << 2) | quad)) ^ ((ma >> 1) & 7)) * 8;
    const int mb = wc * 64 + i * 16 + c16;
    bIdx[i] = (mb >> 1) * 64 + (((((mb & 1) << 2) | quad)) ^ ((mb >> 1) & 7)) * 8;
  }

  auto stage = [&](int k0, int nb) {
#pragma unroll
    for (int rr = 0; rr < 2; ++rr) {
      gload_lds16(A  + aRow[rr] + k0, smem + nb * 4096 + ldsOff[rr]);
      gload_lds16(Wq + wRow[rr] + k0, smem + 8192 + (0 + nb) * 4096 + ldsOff[rr]);
      gload_lds16(Wk + wRow[rr] + k0, smem + 8192 + (2 + nb) * 4096 + ldsOff[rr]);
      gload_lds16(Wv + wRow[rr] + k0, smem + 8192 + (4 + nb) * 4096 + ldsOff[rr]);
    }
  };

  stage(0, 0);   // 8 loads in flight

#pragma unroll 2
  for (int kt = 0; kt < 64; ++kt) {
    const int cb = kt & 1;
    if (kt < 63) {
      stage((kt + 1) * 32, cb ^ 1);   // +8 loads; waited at iter kt+1
      WAITV_BAR(8);                   // wait the 8 OLDER loads (buf cb)
    } else {
      WAITV_BAR(0);
    }

    bf16x8 af[4];
#pragma unroll
    for (int i = 0; i < 4; ++i) af[i] = *(const bf16x8*)&smem[cb * 4096 + aIdx[i]];
#pragma unroll
    for (int z = 0; z < 3; ++z) {
      const bf16* Wb = smem + 8192 + (z * 2 + cb) * 4096;
      bf16x8 bfr[4];
#pragma unroll
      for (int jx = 0; jx < 4; ++jx) bfr[jx] = *(const bf16x8*)&Wb[bIdx[jx]];
#pragma unroll
      for (int i = 0; i < 4; ++i)
#pragma unroll
        for (int jx = 0; jx < 4; ++jx)
          acc[z][i][jx] = MFMA16(af[i], bfr[jx], acc[z][i][jx]);
    }
    BAR();   // all waves done reading cb before iter kt+1 DMA-writes it
  }

  // ---- V epilogue: transposed to (B*H, Dh, S), bf16x4 along s ----
  const int h = n0 >> 7;   // one head per 128-wide n-column
#pragma unroll
  for (int jx = 0; jx < 4; ++jx) {
    const int d = wc * 64 + jx * 16 + c16;
    const float bv = vb[n0 + d];
#pragma unroll
    for (int i = 0; i < 4; ++i) {
      const int row = m0 + wr * 64 + i * 16 + quad * 4;
      const int b = row >> 11, s = row & 2047;
      bf16x4 o;
#pragma unroll
      for (int r = 0; r < 4; ++r) o[r] = (bf16)(acc[2][i][jx][r] + bv);
      *(bf16x4*)&Cv[((size_t)((b * 16 + h) * 128 + d)) * 2048 + s] = o;
    }
  }

  // ---- Q/K epilogues: bias + RoPE via LDS round-trip (pair d <-> d+64
  // crosses waves). Q additionally scaled by log2e/sqrt(Dh) for exp2 softmax.
  bf16* Tl = smem;  // [128][136], 34.8 KB, 16B-aligned rows
#pragma unroll
  for (int z = 0; z < 2; ++z) {
    __syncthreads();   // smem free (main loop done / previous z consumed)
#pragma unroll
    for (int jx = 0; jx < 4; ++jx) {
      const int col = wc * 64 + jx * 16 + c16;
      const float bv = (z == 0 ? qb : kb)[n0 + col];
#pragma unroll
      for (int i = 0; i < 4; ++i) {
        const int row = wr * 64 + i * 16 + quad * 4;
#pragma unroll
        for (int r = 0; r < 4; ++r)
          Tl[(row + r) * 136 + col] = (bf16)(acc[z][i][jx][r] + bv);
      }
    }
    __syncthreads();
    bf16* C = (z == 0) ? Cq : Ck;
    const float scale = (z == 0) ? 0.08838834764831845f * 1.4426950408889634f : 1.0f;
#pragma unroll
    for (int rr = 0; rr < 4; ++rr) {
      const int row = rr * 32 + (t >> 3);
      const int d0 = (t & 7) * 8;
      const int s = (m0 + row) & 2047;
      bf16x8 xa = *(const bf16x8*)&Tl[row * 136 + d0];
      bf16x8 xb = *(const bf16x8*)&Tl[row * 136 + d0 + 64];
      bf16x8 o1, o2;
#pragma unroll
      for (int j = 0; j < 8; ++j) {
        const float inv_freq = __expf((float)(d0 + j) * -0.14391156514261228f);
        float sn, cs;
        __sincosf((float)s * inv_freq, &sn, &cs);
        const float a = (float)xa[j], bb = (float)xb[j];
        o1[j] = (bf16)((a * cs - bb * sn) * scale);
        o2[j] = (bf16)((bb * cs + a * sn) * scale);
      }
      *(bf16x8*)&C[(size_t)(m0 + row) * DM + n0 + d0]      = o1;
      *(bf16x8*)&C[(size_t)(m0 + row) * DM + n0 + d0 + 64] = o2;
    }
  }
}

// Output projection GEMM + bias (fp32 out), v3: BK=32 dbuf + counted vmcnt(4).
// 32 KB LDS -> 3 blocks/CU.
__global__ __launch_bounds__(256, 3) void gemm_bias_f32(
    const bf16* __restrict__ A, const bf16* __restrict__ W,
    const float* __restrict__ bias, float* __restrict__ C)
{
  __shared__ __align__(16) bf16 smem[16384];   // 32 KB: A dbuf 2x4096, B dbuf 2x4096
  const int id = blockIdx.x;               // 512 blocks
  const int xcd = id & 7, jj = id >> 3;
  const int n0 = (xcd * 2 + (jj >> 5)) * 128;
  const int m0 = (jj & 31) * 128;

  const int t = threadIdx.x;
  const int wave = t >> 6, lane = t & 63;
  const int quad = lane >> 4, c16 = lane & 15;
  const int wr = wave >> 1, wc = wave & 1;

  f32x4 acc[4][4] = {};

  size_t aRow[2], bRow[2]; int ldsOff[2];
#pragma unroll
  for (int rr = 0; rr < 2; ++rr) {
    const int g = rr * 256 + t;
    const int r = g >> 3, s = g & 7;
    const int sp = s ^ (r & 7);
    const int m = 2 * r + (sp >> 2), k8 = sp & 3;
    aRow[rr] = (size_t)(m0 + m) * DM + k8 * 8;
    bRow[rr] = (size_t)(n0 + m) * DM + k8 * 8;
    ldsOff[rr] = (rr * 256 + wave * 64) * 8;
  }
  int aIdx[4], bIdx[4];
#pragma unroll
  for (int i = 0; i < 4; ++i) {
    const int ma = wr * 64 + i * 16 + c16;
    aIdx[i] = (ma >> 1) * 64 + (((((ma & 1) << 2) | quad)) ^ ((ma >> 1) & 7)) * 8;
    const int mb = wc * 64 + i * 16 + c16;
    bIdx[i] = (mb >> 1) * 64 + (((((mb & 1) << 2) | quad)) ^ ((mb >> 1) & 7)) * 8;
  }

  auto stage = [&](int k0, int nb) {
#pragma unroll
    for (int rr = 0; rr < 2; ++rr) {
      gload_lds16(A + aRow[rr] + k0, smem + nb * 4096 + ldsOff[rr]);
      gload_lds16(W + bRow[rr] + k0, smem + 8192 + nb * 4096 + ldsOff[rr]);
    }
  };

  stage(0, 0);   // 4 loads in flight

#pragma unroll 2
  for (int kt = 0; kt < 64; ++kt) {
    const int cb = kt & 1;
    if (kt < 63) {
      stage((kt + 1) * 32, cb ^ 1);   // +4 loads; waited at iter kt+1
      WAITV_BAR(4);
    } else {
      WAITV_BAR(0);
    }

    bf16x8 af[4], bfr[4];
#pragma unroll
    for (int i = 0; i < 4; ++i) {
      af[i]  = *(const bf16x8*)&smem[cb * 4096 + aIdx[i]];
      bfr[i] = *(const bf16x8*)&smem[8192 + cb * 4096 + bIdx[i]];
    }
#pragma unroll
    for (int i = 0; i < 4; ++i)
#pragma unroll
      for (int jx = 0; jx < 4; ++jx)
        acc[i][jx] = MFMA16(af[i], bfr[jx], acc[i][jx]);
    BAR();
  }

#pragma unroll
  for (int jx = 0; jx < 4; ++jx) {
    const int col = n0 + wc * 64 + jx * 16 + c16;
    const float bv = bias[col];
#pragma unroll
    for (int i = 0; i < 4; ++i) {
      const int row = m0 + wr * 64 + i * 16 + quad * 4;
#pragma unroll
      for (int r = 0; r < 4; ++r)
        C[(size_t)(row + r) * DM + col] = acc[i][jx][r] + bv;
    }
  }
}

// Flash attention v4: 32x32x16 MFMA, register-resident P (cvt_pk +
// permlane32_swap, T12), 64-key dbuf tiles with COUNTED vmcnt(8) —
// stage(t+1) issued in iter t, waited at top of iter t+1 (full-iter cover).
// Granule-XOR-swizzled K/V LDS (g ^= row&7, pre-swizzled global source).
// QK^T output S^T[key][q]: key=(reg&3)+8*(reg>>2)+4h, q=lane&31; PV B-operand
// needs key=8h+j -> one permlane32_swap per cvt_pk pair. LDS 64 KB.
__global__ __launch_bounds__(256, 2) void attn(
    const bf16* __restrict__ Q, const bf16* __restrict__ K,
    const bf16* __restrict__ Vt, bf16* __restrict__ O)
{
  __shared__ __align__(16) bf16 Ks[2][64][128];   // [buf][key][dh]   32 KB
  __shared__ __align__(16) bf16 Vs[2][128][64];   // [buf][d][key]    32 KB
  const int t = threadIdx.x;
  const int wave = t >> 6, lane = t & 63;
  const int r31 = lane & 31, h = lane >> 5;
  const int id = blockIdx.x;               // 512 blocks
  const int xcd = id & 7, jj = id >> 3;
  const int bh = xcd * 4 + (jj >> 4);
  const int q0 = (jj & 15) * 128;
  const int b = bh >> 4, hd = bh & 15;

  // Q fragments (B-operand): lane holds Q[q = r31][dh = ks*16 + h*8 + j]
  bf16x8 qf[8];
  {
    const bf16* qrow = Q + (size_t)(b * 2048 + q0 + wave * 32 + r31) * 2048
                         + (size_t)hd * 128 + h * 8;
#pragma unroll
    for (int ks = 0; ks < 8; ++ks) qf[ks] = *(const bf16x8*)(qrow + ks * 16);
  }

  float l_i = 0.f;
  f32x16 o_acc[4] = {};   // O^T[d = db*32 + (reg&3)+8*(reg>>2)+4h][q = r31]

  const bf16* Kg = K + (size_t)(b * 2048) * 2048 + (size_t)hd * 128;
  const bf16* Vg = Vt + (size_t)bh * 128 * 2048;

  // stage one 64-key tile (16 KB K + 16 KB V). LDS dest linear; swizzle on
  // the per-lane GLOBAL source column (G21 both-sides-or-neither).
  auto stage = [&](int kt0, int nb) {
#pragma unroll
    for (int rr = 0; rr < 4; ++rr) {
      const int G = rr * 256 + t;
      const int key = G >> 4, gl = G & 15;   // row, 16B-granule in row
      gload_lds16(Kg + (size_t)(kt0 + key) * 2048 + ((gl ^ (key & 7)) * 8),
                  (bf16*)Ks[nb] + (rr * 256 + wave * 64) * 8);
    }
#pragma unroll
    for (int rr = 0; rr < 4; ++rr) {
      const int G = rr * 256 + t;
      const int d = G >> 3, gl = G & 7;
      gload_lds16(Vg + (size_t)d * 2048 + kt0 + ((gl ^ (d & 7)) * 8),
                  (bf16*)Vs[nb] + (rr * 256 + wave * 64) * 8);
    }
  };

  stage(0, 0);   // 8 loads in flight

#pragma unroll 2
  for (int kt = 0; kt < 32; ++kt) {
    const int cb = kt & 1;
    if (kt < 31) {
      stage((kt + 1) * 64, cb ^ 1);   // +8 loads; waited at iter kt+1
      WAITV_BAR(8);
    } else {
      WAITV_BAR(0);
    }

#pragma unroll
    for (int rb = 0; rb < 2; ++rb) {
      // S^T[32 keys][32 q] for key-row-block rb
      f32x16 st = {};
#pragma unroll
      for (int ks = 0; ks < 8; ++ks) {
        const int key = rb * 32 + r31;
        const int g = (2 * ks + h) ^ (key & 7);
        bf16x8 kf = *(const bf16x8*)&Ks[cb][key][g * 8];
        st = MFMA32(kf, qf[ks], st);
      }

      // exp2 softmax (no max); P stays in registers
      float p[16];
#pragma unroll
      for (int r = 0; r < 16; ++r) { p[r] = exp2f(st[r]); l_i += p[r]; }

      // pack pairs: pka[pp] = keys(4h+8pp, +1), pkb[pp] = keys(4h+8pp+2, +3)
      uint32_t pka[4], pkb[4];
#pragma unroll
      for (int pp = 0; pp < 4; ++pp) {
        asm("v_cvt_pk_bf16_f32 %0, %1, %2"
            : "=v"(pka[pp]) : "v"(p[4 * pp + 0]), "v"(p[4 * pp + 1]));
        asm("v_cvt_pk_bf16_f32 %0, %1, %2"
            : "=v"(pkb[pp]) : "v"(p[4 * pp + 2]), "v"(p[4 * pp + 3]));
      }

      // per 16-key chunk c: swap halves -> B-frag words in ascending key order
#pragma unroll
      for (int c = 0; c < 2; ++c) {
        uint32_t a0 = pka[2 * c], a1 = pka[2 * c + 1];
        uint32_t b0 = pkb[2 * c], b1 = pkb[2 * c + 1];
        asm("v_permlane32_swap_b32 %0, %1" : "+v"(a0), "+v"(a1));
        asm("v_permlane32_swap_b32 %0, %1" : "+v"(b0), "+v"(b1));
        union { uint32_t u[4]; bf16x8 v; } pf;
        pf.u[0] = a0; pf.u[1] = b0; pf.u[2] = a1; pf.u[3] = b1;
        const int kap = rb * 2 + c;   // 16-key chunk within the 64-key tile
#pragma unroll
        for (int db = 0; db < 4; ++db) {
          const int d = db * 32 + r31;
          const int g = (2 * kap + h) ^ (d & 7);
          bf16x8 vf = *(const bf16x8*)&Vs[cb][d][g * 8];
          o_acc[db] = MFMA32(vf, pf.v, o_acc[db]);
        }
      }
    }
    BAR();   // all waves done reading cb before iter kt+1 DMA-writes it
  }

  // epilogue: l reduce across the two key-halves (h pair), normalize, write O
  l_i += __shfl_xor(l_i, 32, 64);
  const float invl = 1.0f / l_i;
  const int q = q0 + wave * 32 + r31;
  bf16* orow = O + (size_t)(b * 2048 + q) * 2048 + (size_t)hd * 128;
#pragma unroll
  for (int db = 0; db < 4; ++db)
#pragma unroll
    for (int pp = 0; pp < 4; ++pp) {
      const int d0 = db * 32 + 8 * pp + 4 * h;
      bf16x4 o;
#pragma unroll
      for (int r = 0; r < 4; ++r) o[r] = (bf16)(o_acc[db][4 * pp + r] * invl);
      *(bf16x4*)(orow + d0) = o;
    }
}

extern "C" void kernel_launch(void* const* d_in, const int* in_sizes, int n_in,
                              void* d_out, int out_size, void* d_ws, size_t ws_size,
                              hipStream_t stream)
{
  (void)in_sizes; (void)n_in; (void)out_size; (void)ws_size;
  const float* x   = (const float*)d_in[0];
  const float* q_w = (const float*)d_in[1];
  const float* k_w = (const float*)d_in[2];
  const float* v_w = (const float*)d_in[3];
  const float* q_b = (const float*)d_in[4];
  const float* k_b = (const float*)d_in[5];
  const float* v_b = (const float*)d_in[6];
  const float* o_w = (const float*)d_in[7];
  const float* o_b = (const float*)d_in[8];

  const size_t NELEM = (size_t)MM * DM;   // 8388608
  const size_t WELEM = (size_t)DM * DM;   // 4194304
  bf16* Xb  = (bf16*)d_ws;                // reused as attnO (x dead by then)
  bf16* Wq  = Xb + NELEM;
  bf16* Wk  = Wq + WELEM;
  bf16* Wv  = Wk + WELEM;
  bf16* Wo  = Wv + WELEM;
  bf16* Q   = Wo + WELEM;
  bf16* Kb  = Q  + NELEM;
  bf16* Vt  = Kb + NELEM;
  bf16* attnO = Xb;

  cvt_f32_bf16<<<24576, 256, 0, stream>>>(x, q_w, k_w, v_w, o_w, Xb, Wq, Wk, Wv, Wo);

  gemm_qkv_fused<<<512, 256, 0, stream>>>(Xb, Wq, Wk, Wv, q_b, k_b, v_b, Q, Kb, Vt);
  attn<<<512, 256, 0, stream>>>(Q, Kb, Vt, attnO);
  gemm_bias_f32<<<512, 256, 0, stream>>>(attnO, Wo, o_b, (float*)d_out);
}

// Round 6
// 378.089 us; speedup vs baseline: 1.0256x; 1.0154x over previous
//
#include <hip/hip_runtime.h>
#include <stdint.h>

typedef __bf16 bf16;
typedef __bf16 bf16x4 __attribute__((ext_vector_type(4)));
typedef __bf16 bf16x8 __attribute__((ext_vector_type(8)));
typedef float f32x4 __attribute__((ext_vector_type(4)));
typedef float f32x16 __attribute__((ext_vector_type(16)));

#define DM 2048   // embed dim = N = K of GEMMs
#define MM 4096   // B*S rows
#define MFMA16(a, b, c) __builtin_amdgcn_mfma_f32_16x16x32_bf16(a, b, c, 0, 0, 0)
#define MFMA32(a, b, c) __builtin_amdgcn_mfma_f32_32x32x16_bf16(a, b, c, 0, 0, 0)

// counted-vmcnt barrier pair (T4): wait only the N newest-excluded loads.
#define WAITV_BAR(N) asm volatile("s_waitcnt vmcnt(" #N ")\n\ts_barrier" ::: "memory")
#define BAR()        asm volatile("s_barrier" ::: "memory")

__device__ __forceinline__ void gload_lds16(const void* g, void* l) {
  __builtin_amdgcn_global_load_lds((const __attribute__((address_space(1))) uint32_t*)g,
                                   (__attribute__((address_space(3))) uint32_t*)l, 16, 0, 0);
}

// fp32 -> bf16 for x (8.4M) and the 4 weight matrices (4.2M each).
__global__ __launch_bounds__(256) void cvt_f32_bf16(
    const float* __restrict__ s0, const float* __restrict__ s1,
    const float* __restrict__ s2, const float* __restrict__ s3,
    const float* __restrict__ s4,
    bf16* __restrict__ d0, bf16* __restrict__ d1, bf16* __restrict__ d2,
    bf16* __restrict__ d3, bf16* __restrict__ d4)
{
  const size_t i4 = (size_t)(blockIdx.x * 256 + threadIdx.x) * 4;  // float index
  const float* s; bf16* d; size_t off;
  if      (i4 <  8388608u) { s = s0; d = d0; off = i4;             }
  else if (i4 < 12582912u) { s = s1; d = d1; off = i4 -  8388608u; }
  else if (i4 < 16777216u) { s = s2; d = d2; off = i4 - 12582912u; }
  else if (i4 < 20971520u) { s = s3; d = d3; off = i4 - 16777216u; }
  else                     { s = s4; d = d4; off = i4 - 20971520u; }
  const float4 v = *(const float4*)(s + off);
  bf16x4 o = { (bf16)v.x, (bf16)v.y, (bf16)v.z, (bf16)v.w };
  *(bf16x4*)(d + off) = o;
}

// Fused QKV projection — R2 structure (proven 96 us, MfmaUtil 48%): BK=64,
// 2-barrier loop, XOR-swizzled LDS, A staged once for 96 MFMAs/k-step.
// RoPE + softmax-scale fused into Q/K epilogues. V written transposed.
// XCD swizzle: each XCD owns 2 n-columns (3 MB weights L2-resident).
__global__ __launch_bounds__(256, 2) void gemm_qkv_fused(
    const bf16* __restrict__ A,
    const bf16* __restrict__ Wq, const bf16* __restrict__ Wk, const bf16* __restrict__ Wv,
    const float* __restrict__ qb, const float* __restrict__ kb, const float* __restrict__ vb,
    bf16* __restrict__ Cq, bf16* __restrict__ Ck, bf16* __restrict__ Cv)
{
  __shared__ __align__(16) bf16 smem[32768];   // 64 KB
  bf16* As = smem;           // [128][64]
  bf16* Ws = smem + 8192;    // 3 x [128][64]

  const int id = blockIdx.x;               // 512 blocks
  const int xcd = id & 7, jj = id >> 3;
  const int n0 = (xcd * 2 + (jj >> 5)) * 128;
  const int m0 = (jj & 31) * 128;

  const int t = threadIdx.x;
  const int wave = t >> 6, lane = t & 63;
  const int quad = lane >> 4, c16 = lane & 15;
  const int wr = wave >> 1, wc = wave & 1;

  f32x4 acc[3][4][4] = {};

  // staging: granule g=rr*256+t -> LDS row=g>>3, slot=g&7; global column
  // granule = slot ^ (row&7)  (XOR swizzle; permutes within a 128B segment)
  const int srow = t >> 3;
  const int scol = ((t & 7) ^ (srow & 7)) * 8;
  const bf16* gA  = A  + (size_t)(m0 + srow) * DM + scol;
  const bf16* gW0 = Wq + (size_t)(n0 + srow) * DM + scol;
  const bf16* gW1 = Wk + (size_t)(n0 + srow) * DM + scol;
  const bf16* gW2 = Wv + (size_t)(n0 + srow) * DM + scol;

  for (int k0 = 0; k0 < DM; k0 += 64) {
#pragma unroll
    for (int rr = 0; rr < 4; ++rr) {
      const size_t go = (size_t)(rr * 32) * DM;
      const int lo = (rr * 256 + wave * 64) * 8;
      gload_lds16(gA  + go, As + lo);
      gload_lds16(gW0 + go, Ws + lo);
      gload_lds16(gW1 + go, Ws + 8192 + lo);
      gload_lds16(gW2 + go, Ws + 16384 + lo);
    }
    gA += 64; gW0 += 64; gW1 += 64; gW2 += 64;
    __syncthreads();

#pragma unroll
    for (int ks = 0; ks < 2; ++ks) {
      bf16x8 af[4];
#pragma unroll
      for (int i = 0; i < 4; ++i) {
        const int row = wr * 64 + i * 16 + c16;
        const int gi = (ks * 4 + quad) ^ (row & 7);
        af[i] = *(const bf16x8*)&As[row * 64 + gi * 8];
      }
#pragma unroll
      for (int z = 0; z < 3; ++z) {
        bf16x8 bfr[4];
#pragma unroll
        for (int jx = 0; jx < 4; ++jx) {
          const int row = wc * 64 + jx * 16 + c16;
          const int gi = (ks * 4 + quad) ^ (row & 7);
          bfr[jx] = *(const bf16x8*)&Ws[z * 8192 + row * 64 + gi * 8];
        }
#pragma unroll
        for (int i = 0; i < 4; ++i)
#pragma unroll
          for (int jx = 0; jx < 4; ++jx)
            acc[z][i][jx] = MFMA16(af[i], bfr[jx], acc[z][i][jx]);
      }
    }
    __syncthreads();
  }

  // ---- V epilogue: transposed to (B*H, Dh, S), bf16x4 along s ----
  const int h = n0 >> 7;   // one head per 128-wide n-column
#pragma unroll
  for (int jx = 0; jx < 4; ++jx) {
    const int d = wc * 64 + jx * 16 + c16;
    const float bv = vb[n0 + d];
#pragma unroll
    for (int i = 0; i < 4; ++i) {
      const int row = m0 + wr * 64 + i * 16 + quad * 4;
      const int b = row >> 11, s = row & 2047;
      bf16x4 o;
#pragma unroll
      for (int r = 0; r < 4; ++r) o[r] = (bf16)(acc[2][i][jx][r] + bv);
      *(bf16x4*)&Cv[((size_t)((b * 16 + h) * 128 + d)) * 2048 + s] = o;
    }
  }

  // ---- Q/K epilogues: bias + RoPE via LDS round-trip (pair d <-> d+64
  // crosses waves). Q additionally scaled by log2e/sqrt(Dh) for exp2 softmax.
  bf16* Tl = smem;  // [128][136], 34.8 KB, 16B-aligned rows
#pragma unroll
  for (int z = 0; z < 2; ++z) {
    __syncthreads();   // smem free (main loop done / previous z consumed)
#pragma unroll
    for (int jx = 0; jx < 4; ++jx) {
      const int col = wc * 64 + jx * 16 + c16;
      const float bv = (z == 0 ? qb : kb)[n0 + col];
#pragma unroll
      for (int i = 0; i < 4; ++i) {
        const int row = wr * 64 + i * 16 + quad * 4;
#pragma unroll
        for (int r = 0; r < 4; ++r)
          Tl[(row + r) * 136 + col] = (bf16)(acc[z][i][jx][r] + bv);
      }
    }
    __syncthreads();
    bf16* C = (z == 0) ? Cq : Ck;
    const float scale = (z == 0) ? 0.08838834764831845f * 1.4426950408889634f : 1.0f;
#pragma unroll
    for (int rr = 0; rr < 4; ++rr) {
      const int row = rr * 32 + (t >> 3);
      const int d0 = (t & 7) * 8;
      const int s = (m0 + row) & 2047;
      bf16x8 xa = *(const bf16x8*)&Tl[row * 136 + d0];
      bf16x8 xb = *(const bf16x8*)&Tl[row * 136 + d0 + 64];
      bf16x8 o1, o2;
#pragma unroll
      for (int j = 0; j < 8; ++j) {
        const float inv_freq = __expf((float)(d0 + j) * -0.14391156514261228f);
        float sn, cs;
        __sincosf((float)s * inv_freq, &sn, &cs);
        const float a = (float)xa[j], bb = (float)xb[j];
        o1[j] = (bf16)((a * cs - bb * sn) * scale);
        o2[j] = (bf16)((bb * cs + a * sn) * scale);
      }
      *(bf16x8*)&C[(size_t)(m0 + row) * DM + n0 + d0]      = o1;
      *(bf16x8*)&C[(size_t)(m0 + row) * DM + n0 + d0 + 64] = o2;
    }
  }
}

// Output projection GEMM + bias (fp32 out) — R2 structure (BK=64, 2-barrier).
__global__ __launch_bounds__(256, 2) void gemm_bias_f32(
    const bf16* __restrict__ A, const bf16* __restrict__ W,
    const float* __restrict__ bias, float* __restrict__ C)
{
  __shared__ __align__(16) bf16 As[8192];   // [128][64]
  __shared__ __align__(16) bf16 Bs[8192];
  const int id = blockIdx.x;               // 512 blocks
  const int xcd = id & 7, jj = id >> 3;
  const int n0 = (xcd * 2 + (jj >> 5)) * 128;
  const int m0 = (jj & 31) * 128;

  const int t = threadIdx.x;
  const int wave = t >> 6, lane = t & 63;
  const int quad = lane >> 4, c16 = lane & 15;
  const int wr = wave >> 1, wc = wave & 1;

  f32x4 acc[4][4] = {};
  const int srow = t >> 3;
  const int scol = ((t & 7) ^ (srow & 7)) * 8;
  const bf16* gA = A + (size_t)(m0 + srow) * DM + scol;
  const bf16* gB = W + (size_t)(n0 + srow) * DM + scol;

  for (int k0 = 0; k0 < DM; k0 += 64) {
#pragma unroll
    for (int rr = 0; rr < 4; ++rr) {
      const size_t go = (size_t)(rr * 32) * DM;
      const int lo = (rr * 256 + wave * 64) * 8;
      gload_lds16(gA + go, As + lo);
      gload_lds16(gB + go, Bs + lo);
    }
    gA += 64; gB += 64;
    __syncthreads();

#pragma unroll
    for (int ks = 0; ks < 2; ++ks) {
      bf16x8 af[4], bfr[4];
#pragma unroll
      for (int i = 0; i < 4; ++i) {
        const int row = wr * 64 + i * 16 + c16;
        const int gi = (ks * 4 + quad) ^ (row & 7);
        af[i] = *(const bf16x8*)&As[row * 64 + gi * 8];
      }
#pragma unroll
      for (int jx = 0; jx < 4; ++jx) {
        const int row = wc * 64 + jx * 16 + c16;
        const int gi = (ks * 4 + quad) ^ (row & 7);
        bfr[jx] = *(const bf16x8*)&Bs[row * 64 + gi * 8];
      }
#pragma unroll
      for (int i = 0; i < 4; ++i)
#pragma unroll
        for (int jx = 0; jx < 4; ++jx)
          acc[i][jx] = MFMA16(af[i], bfr[jx], acc[i][jx]);
    }
    __syncthreads();
  }

#pragma unroll
  for (int jx = 0; jx < 4; ++jx) {
    const int col = n0 + wc * 64 + jx * 16 + c16;
    const float bv = bias[col];
#pragma unroll
    for (int i = 0; i < 4; ++i) {
      const int row = m0 + wr * 64 + i * 16 + quad * 4;
#pragma unroll
      for (int r = 0; r < 4; ++r)
        C[(size_t)(row + r) * DM + col] = acc[i][jx][r] + bv;
    }
  }
}

// Flash attention v5: q-direction register blocking — each wave owns 64 q-rows
// (2 q-sub-blocks of 32), so every K-frag ds_read feeds 2 QK^T MFMAs and
// every V-frag read feeds 2 PV MFMAs (2:1 MFMA:read, GEMM-like). Block =
// 256 q-rows -> grid 256 = 1 block/CU; LDS 64 KB dbuf; VGPR ~290 (fine at
// 4 waves/CU). Register-P via cvt_pk + permlane32_swap (T12); counted
// vmcnt(8) prefetch (full-iteration cover, ~2000 cy compute per tile).
__global__ __launch_bounds__(256, 1) void attn(
    const bf16* __restrict__ Q, const bf16* __restrict__ K,
    const bf16* __restrict__ Vt, bf16* __restrict__ O)
{
  __shared__ __align__(16) bf16 Ks[2][64][128];   // [buf][key][dh]   32 KB
  __shared__ __align__(16) bf16 Vs[2][128][64];   // [buf][d][key]    32 KB
  const int t = threadIdx.x;
  const int wave = t >> 6, lane = t & 63;
  const int r31 = lane & 31, h = lane >> 5;
  const int id = blockIdx.x;               // 256 blocks
  const int xcd = id & 7, jj = id >> 3;    // jj in 0..31
  const int bh = xcd * 4 + (jj >> 3);      // 4 heads/XCD (4 MB K/V = L2)
  const int q0 = (jj & 7) * 256;
  const int b = bh >> 4, hd = bh & 15;

  // Q fragments (B-operand), 2 q-sub-blocks: lane holds Q[q][dh=ks*16+h*8+j]
  bf16x8 qf[2][8];
#pragma unroll
  for (int qs = 0; qs < 2; ++qs) {
    const bf16* qrow = Q + (size_t)(b * 2048 + q0 + wave * 64 + qs * 32 + r31) * 2048
                         + (size_t)hd * 128 + h * 8;
#pragma unroll
    for (int ks = 0; ks < 8; ++ks) qf[qs][ks] = *(const bf16x8*)(qrow + ks * 16);
  }

  float l_i[2] = {0.f, 0.f};
  f32x16 o_acc[2][4] = {};   // [qsub][db]: O^T[d=db*32+(reg&3)+8*(reg>>2)+4h][q=r31]

  const bf16* Kg = K + (size_t)(b * 2048) * 2048 + (size_t)hd * 128;
  const bf16* Vg = Vt + (size_t)bh * 128 * 2048;

  // stage one 64-key tile (16 KB K + 16 KB V); 8 gload_lds16 per thread.
  // LDS dest linear; swizzle on the per-lane GLOBAL source column (G21).
  auto stage = [&](int kt0, int nb) {
#pragma unroll
    for (int rr = 0; rr < 4; ++rr) {
      const int G = rr * 256 + t;
      const int key = G >> 4, gl = G & 15;   // row, 16B-granule in row
      gload_lds16(Kg + (size_t)(kt0 + key) * 2048 + ((gl ^ (key & 7)) * 8),
                  (bf16*)Ks[nb] + (rr * 256 + wave * 64) * 8);
    }
#pragma unroll
    for (int rr = 0; rr < 4; ++rr) {
      const int G = rr * 256 + t;
      const int d = G >> 3, gl = G & 7;
      gload_lds16(Vg + (size_t)d * 2048 + kt0 + ((gl ^ (d & 7)) * 8),
                  (bf16*)Vs[nb] + (rr * 256 + wave * 64) * 8);
    }
  };

  stage(0, 0);   // 8 loads in flight

  for (int kt = 0; kt < 32; ++kt) {
    const int cb = kt & 1;
    if (kt < 31) {
      stage((kt + 1) * 64, cb ^ 1);   // +8 loads; waited at iter kt+1
      WAITV_BAR(8);
    } else {
      WAITV_BAR(0);
    }

#pragma unroll
    for (int rb = 0; rb < 2; ++rb) {
      // S^T[32 keys][32 q] for both q-sub-blocks; kf shared across qs
      f32x16 st[2] = {};
#pragma unroll
      for (int ks = 0; ks < 8; ++ks) {
        const int key = rb * 32 + r31;
        const int g = (2 * ks + h) ^ (key & 7);
        bf16x8 kf = *(const bf16x8*)&Ks[cb][key][g * 8];
        st[0] = MFMA32(kf, qf[0][ks], st[0]);
        st[1] = MFMA32(kf, qf[1][ks], st[1]);
      }

      // exp2 softmax (no max) + pack to PV B-fragments, per q-sub-block
      uint32_t pf[2][2][4];   // [qsub][16-key chunk][word]; all idx compile-time
#pragma unroll
      for (int qs = 0; qs < 2; ++qs) {
        float p[16];
#pragma unroll
        for (int r = 0; r < 16; ++r) { p[r] = exp2f(st[qs][r]); l_i[qs] += p[r]; }
        uint32_t pka[4], pkb[4];
#pragma unroll
        for (int pp = 0; pp < 4; ++pp) {
          asm("v_cvt_pk_bf16_f32 %0, %1, %2"
              : "=v"(pka[pp]) : "v"(p[4 * pp + 0]), "v"(p[4 * pp + 1]));
          asm("v_cvt_pk_bf16_f32 %0, %1, %2"
              : "=v"(pkb[pp]) : "v"(p[4 * pp + 2]), "v"(p[4 * pp + 3]));
        }
#pragma unroll
        for (int c = 0; c < 2; ++c) {
          uint32_t a0 = pka[2 * c], a1 = pka[2 * c + 1];
          uint32_t b0 = pkb[2 * c], b1 = pkb[2 * c + 1];
          asm("v_permlane32_swap_b32 %0, %1" : "+v"(a0), "+v"(a1));
          asm("v_permlane32_swap_b32 %0, %1" : "+v"(b0), "+v"(b1));
          pf[qs][c][0] = a0; pf[qs][c][1] = b0; pf[qs][c][2] = a1; pf[qs][c][3] = b1;
        }
      }

      // O^T += V^T P^T; vf shared across both q-sub-blocks
#pragma unroll
      for (int c = 0; c < 2; ++c) {
        const int kap = rb * 2 + c;
        union { uint32_t u[4]; bf16x8 v; } p0, p1;
#pragma unroll
        for (int w = 0; w < 4; ++w) { p0.u[w] = pf[0][c][w]; p1.u[w] = pf[1][c][w]; }
#pragma unroll
        for (int db = 0; db < 4; ++db) {
          const int d = db * 32 + r31;
          const int g = (2 * kap + h) ^ (d & 7);
          bf16x8 vf = *(const bf16x8*)&Vs[cb][d][g * 8];
          o_acc[0][db] = MFMA32(vf, p0.v, o_acc[0][db]);
          o_acc[1][db] = MFMA32(vf, p1.v, o_acc[1][db]);
        }
      }
    }
    BAR();   // all waves done reading cb before iter kt+1 DMA-writes it
  }

  // epilogue: l reduce across the two key-halves (h pair), normalize, write O
#pragma unroll
  for (int qs = 0; qs < 2; ++qs) {
    float l = l_i[qs];
    l += __shfl_xor(l, 32, 64);
    const float invl = 1.0f / l;
    const int q = q0 + wave * 64 + qs * 32 + r31;
    bf16* orow = O + (size_t)(b * 2048 + q) * 2048 + (size_t)hd * 128;
#pragma unroll
    for (int db = 0; db < 4; ++db)
#pragma unroll
      for (int pp = 0; pp < 4; ++pp) {
        const int d0 = db * 32 + 8 * pp + 4 * h;
        bf16x4 o;
#pragma unroll
        for (int r = 0; r < 4; ++r) o[r] = (bf16)(o_acc[qs][db][4 * pp + r] * invl);
        *(bf16x4*)(orow + d0) = o;
      }
  }
}

extern "C" void kernel_launch(void* const* d_in, const int* in_sizes, int n_in,
                              void* d_out, int out_size, void* d_ws, size_t ws_size,
                              hipStream_t stream)
{
  (void)in_sizes; (void)n_in; (void)out_size; (void)ws_size;
  const float* x   = (const float*)d_in[0];
  const float* q_w = (const float*)d_in[1];
  const float* k_w = (const float*)d_in[2];
  const float* v_w = (const float*)d_in[3];
  const float* q_b = (const float*)d_in[4];
  const float* k_b = (const float*)d_in[5];
  const float* v_b = (const float*)d_in[6];
  const float* o_w = (const float*)d_in[7];
  const float* o_b = (const float*)d_in[8];

  const size_t NELEM = (size_t)MM * DM;   // 8388608
  const size_t WELEM = (size_t)DM * DM;   // 4194304
  bf16* Xb  = (bf16*)d_ws;                // reused as attnO (x dead by then)
  bf16* Wq  = Xb + NELEM;
  bf16* Wk  = Wq + WELEM;
  bf16* Wv  = Wk + WELEM;
  bf16* Wo  = Wv + WELEM;
  bf16* Q   = Wo + WELEM;
  bf16* Kb  = Q  + NELEM;
  bf16* Vt  = Kb + NELEM;
  bf16* attnO = Xb;

  cvt_f32_bf16<<<24576, 256, 0, stream>>>(x, q_w, k_w, v_w, o_w, Xb, Wq, Wk, Wv, Wo);

  gemm_qkv_fused<<<512, 256, 0, stream>>>(Xb, Wq, Wk, Wv, q_b, k_b, v_b, Q, Kb, Vt);
  attn<<<256, 256, 0, stream>>>(Q, Kb, Vt, attnO);
  gemm_bias_f32<<<512, 256, 0, stream>>>(attnO, Wo, o_b, (float*)d_out);
}